// Round 4
// baseline (195.385 us; speedup 1.0000x reference)
//
#include <hip/hip_runtime.h>

// EdgeNetwork: counting-sort + MFMA + run-merged atomic scatter. 5 dispatches.
//
// Journal:
// R0: coop-launch fusion silently no-ops under graph capture. NEVER coop here.
// R1: occupancy x2 under 12.8M-atomic wall -> neutral/negative. Wall = atomic
//     dword rate (~225G/s) at the coherence point, not latency.
// R3: dst-sort + in-register run-merge (8 consecutive sorted edges per lane)
//     cut atomics ~3x; edge_sorted dropped 57 -> <43us. Regression to 172us
//     came from sort-chain kernels + launches, not the MFMA kernel.
// R4 (this): consolidate. k_scan claims chunk bases via atomicAdd (group order
//     across chunks need not be monotone -- merge tests equality only, CSR
//     ranges just need disjointness) -> k_scan_tops eliminated, no boff.
//     NBLK 768->1024 + launch_bounds(256,4): atomic wall shrank, kernel now
//     gather-latency-limited -> TLP should pay where it didn't in R1.

typedef _Float16 half8 __attribute__((ext_vector_type(8)));
typedef _Float16 half4t __attribute__((ext_vector_type(4)));
typedef float float4v __attribute__((ext_vector_type(4)));

constexpr int NA = 100000;
constexpr int E  = 400000;
constexpr int TILES = E / 32;          // 12500
constexpr int NBLK  = 1024;            // 4 blocks/CU
constexpr int HALFW = NBLK * 4 / 2;    // 2048 waves per column-half
constexpr int NCHUNK = (NA + 1023) / 1024;   // 98 scan chunks

// ---- workspace layout (bytes) ----
constexpr size_t OFF_ATOMH = 0;                          // f16[NA*32]   6.40 MB
constexpr size_t OFF_BONDS = (size_t)NA * 32 * 2;        // f16[E*16]   12.80 MB (sorted)
constexpr size_t OFF_PAIRS = OFF_BONDS + (size_t)E*16*2; // int2[E]      3.20 MB (sorted)
constexpr size_t OFF_HIST  = OFF_PAIRS + (size_t)E*8;    // u32[NA]      0.40 MB
constexpr size_t OFF_BASE  = OFF_HIST + (size_t)NA*4;    // u32[NA]      0.40 MB
constexpr size_t OFF_CNT   = OFF_BASE + (size_t)NA*4;    // u32[1]

constexpr int NZ4 = NA * 32 / 4;   // out zeroing, float4 units   (800k)
constexpr int NA4 = NA * 32 / 4;   // atom convert, float4 units  (800k)
constexpr int NH4 = NA / 4;        // hist zeroing, uint4 units   (25k)
constexpr int K0_TOT = NZ4 + NA4 + NH4;

// ---- k0: zero out + zero hist + zero counter + convert atom f32->f16 ----
__global__ void k_zero_conv(const float* __restrict__ atom,
                            float4* __restrict__ outz,
                            half4t* __restrict__ atomh4,
                            uint4* __restrict__ histz,
                            unsigned* __restrict__ counter) {
  int i = blockIdx.x * 256 + threadIdx.x;
  if (i < NZ4) {
    outz[i] = make_float4(0.f, 0.f, 0.f, 0.f);
  } else if (i < NZ4 + NA4) {
    int k = i - NZ4;
    float4 v = ((const float4*)atom)[k];
    half4t hh = { (_Float16)v.x, (_Float16)v.y, (_Float16)v.z, (_Float16)v.w };
    atomh4[k] = hh;
  } else if (i < K0_TOT) {
    int k = i - NZ4 - NA4;
    histz[k] = make_uint4(0u, 0u, 0u, 0u);
  } else if (i == K0_TOT) {
    *counter = 0u;
  }
}

// ---- k1: histogram of destinations (must follow hist zeroing -> own kernel)
__global__ void k_hist(const int2* __restrict__ pairs2,
                       unsigned* __restrict__ hist) {
  int e = blockIdx.x * 256 + threadIdx.x;
  if (e >= E) return;
  atomicAdd(&hist[(unsigned)pairs2[e].x], 1u);
}

// ---- k2: per-1024-chunk scan; chunk base claimed via atomicAdd (order-free).
// base[d] = FINAL global start of dst d's group.
__global__ void k_scan(const unsigned* __restrict__ hist,
                       unsigned* __restrict__ base,
                       unsigned* __restrict__ counter) {
  __shared__ unsigned s[256];
  __shared__ unsigned cbase;
  const int t  = threadIdx.x;
  const int i0 = blockIdx.x * 1024 + t * 4;
  unsigned c[4], sum = 0;
  #pragma unroll
  for (int j = 0; j < 4; ++j) {
    unsigned v = (i0 + j < NA) ? hist[i0 + j] : 0u;
    c[j] = v; sum += v;
  }
  s[t] = sum;
  __syncthreads();
  for (int off = 1; off < 256; off <<= 1) {   // Hillis-Steele inclusive
    unsigned v = (t >= off) ? s[t - off] : 0u;
    __syncthreads();
    s[t] += v;
    __syncthreads();
  }
  if (t == 255) cbase = atomicAdd(counter, s[255]);
  __syncthreads();
  unsigned run = cbase + ((t == 0) ? 0u : s[t - 1]);
  #pragma unroll
  for (int j = 0; j < 4; ++j) {
    if (i0 + j < NA) base[i0 + j] = run;
    run += c[j];
  }
}

// ---- k3: scatter edges into dst-grouped order; convert bond rows to f16 ----
__global__ void k_scatter(const int2* __restrict__ pairs2,
                          const float4* __restrict__ bondf4,
                          unsigned* __restrict__ hist,
                          const unsigned* __restrict__ base,
                          int2* __restrict__ pairs_s,
                          half8* __restrict__ bondh_s) {
  int e = blockIdx.x * 256 + threadIdx.x;
  if (e >= E) return;
  int2 p = pairs2[e];
  unsigned d = (unsigned)p.x;
  unsigned pos = base[d] + (atomicSub(&hist[d], 1u) - 1u);
  pairs_s[pos] = p;
  float4 b0 = bondf4[e * 4 + 0], b1 = bondf4[e * 4 + 1];
  float4 b2 = bondf4[e * 4 + 2], b3 = bondf4[e * 4 + 3];
  half8 h0 = { (_Float16)b0.x, (_Float16)b0.y, (_Float16)b0.z, (_Float16)b0.w,
               (_Float16)b1.x, (_Float16)b1.y, (_Float16)b1.z, (_Float16)b1.w };
  half8 h1 = { (_Float16)b2.x, (_Float16)b2.y, (_Float16)b2.z, (_Float16)b2.w,
               (_Float16)b3.x, (_Float16)b3.y, (_Float16)b3.z, (_Float16)b3.w };
  bondh_s[(size_t)pos * 2 + 0] = h0;
  bondh_s[(size_t)pos * 2 + 1] = h1;
}

static __device__ inline half8 splat8(_Float16 v) {
  half8 r = {v, v, v, v, v, v, v, v};
  return r;
}

// ---- k4: MFMA GEMM + run-merged scatter over dst-grouped edges ----
// Edge->row permutation: (acc0, rowA=q*4+r) <-> local edge q*8+r;
// (acc1, rowB) <-> local edge q*8+4+r. Lane (q,el)'s 8 acc values are edges
// q*8+0..7 in grouped order -> merge equal-dst runs before atomics.
__global__ __launch_bounds__(256, 4)
void edge_sorted(const _Float16* __restrict__ atomh,
                 const _Float16* __restrict__ bondh,
                 const int* __restrict__ pairs_s,
                 const float* __restrict__ Kmat,
                 const float* __restrict__ bias,
                 float* __restrict__ out)
{
  const int tid  = threadIdx.x;
  const int lane = tid & 63;
  const int wid  = blockIdx.x * 4 + (tid >> 6);
  const int h    = wid & 1;          // column half this wave owns
  const int q    = lane >> 4;
  const int el   = lane & 15;
  const int n    = el + h * 16;      // output column
  const int j0   = q * 8;
  const int eA   = ((el >> 2) * 8) + (el & 3);   // local edge for A-row el

  // W fragments for all 17 K-steps, register-resident.
  half8 Wr[17];
  #pragma unroll
  for (int s = 0; s < 17; ++s) {
    const float* src = (s < 16) ? (Kmat + s * 1024 + n * 32 + j0)
                                : (bias + n * 32 + j0);
    half8 w;
    #pragma unroll
    for (int j = 0; j < 8; ++j) w[j] = (_Float16)src[j];
    Wr[s] = w;
  }

  const int start  = wid >> 1;
  const int stride = HALFW;
  const int2* pairs2 = (const int2*)pairs_s;

  auto ldpv = [&](int t) -> int2 {
    const int tc = t < TILES ? t : TILES - 1;   // clamp: loads stay valid
    int2 v = make_int2(0, 0);
    if (lane < 32) v = pairs2[tc * 32 + lane];
    return v;
  };

  // ---- Pipeline prologue.
  int2 pv0 = ldpv(start);
  int2 pv1 = ldpv(start + stride);

  half8 nbA_c, nbB_c, bA0_c, bA1_c, bB0_c, bB1_c;
  {
    const int aA = __shfl(pv0.y, eA);
    const int aB = __shfl(pv0.y, eA + 4);
    nbA_c = *(const half8*)(atomh + (size_t)aA * 32 + j0);
    nbB_c = *(const half8*)(atomh + (size_t)aB * 32 + j0);
    const _Float16* brA = bondh + (size_t)(start * 32 + eA) * 16;
    const _Float16* brB = bondh + (size_t)(start * 32 + eA + 4) * 16;
    bA0_c = *(const half8*)(brA);  bA1_c = *(const half8*)(brA + 8);
    bB0_c = *(const half8*)(brB);  bB1_c = *(const half8*)(brB + 8);
  }

  for (int t = start; t < TILES; t += stride) {
    const int tn = t + stride;

    // ---- Stage next tile (loads in flight across this tile's compute).
    half8 nbA_n, nbB_n, bA0_n, bA1_n, bB0_n, bB1_n;
    {
      const int aA = __shfl(pv1.y, eA);
      const int aB = __shfl(pv1.y, eA + 4);
      nbA_n = *(const half8*)(atomh + (size_t)aA * 32 + j0);
      nbB_n = *(const half8*)(atomh + (size_t)aB * 32 + j0);
      const int tc = tn < TILES ? tn : TILES - 1;
      const _Float16* brA = bondh + (size_t)(tc * 32 + eA) * 16;
      const _Float16* brB = bondh + (size_t)(tc * 32 + eA + 4) * 16;
      bA0_n = *(const half8*)(brA);  bA1_n = *(const half8*)(brA + 8);
      bB0_n = *(const half8*)(brB);  bB1_n = *(const half8*)(brB + 8);
    }
    const int2 pv2 = ldpv(tn + stride);

    // ---- Compute current tile.
    float4v acc0 = {0.f, 0.f, 0.f, 0.f};
    float4v acc1 = {0.f, 0.f, 0.f, 0.f};
    #pragma unroll
    for (int s = 0; s < 16; ++s) {
      const _Float16 sA = (s < 8) ? bA0_c[s] : bA1_c[s - 8];
      const _Float16 sB = (s < 8) ? bB0_c[s] : bB1_c[s - 8];
      const half8 aAf = nbA_c * splat8(sA);
      const half8 aBf = nbB_c * splat8(sB);
      acc0 = __builtin_amdgcn_mfma_f32_16x16x32_f16(aAf, Wr[s], acc0, 0, 0, 0);
      acc1 = __builtin_amdgcn_mfma_f32_16x16x32_f16(aBf, Wr[s], acc1, 0, 0, 0);
    }
    acc0 = __builtin_amdgcn_mfma_f32_16x16x32_f16(nbA_c, Wr[16], acc0, 0, 0, 0);
    acc1 = __builtin_amdgcn_mfma_f32_16x16x32_f16(nbB_c, Wr[16], acc1, 0, 0, 0);

    // ---- Epilogue: merge equal-dst runs over the lane's 8 grouped edges.
    {
      int   cur = __shfl(pv0.x, q * 8);
      float run = acc0[0];
      #pragma unroll
      for (int m = 1; m < 8; ++m) {
        const float v  = (m < 4) ? acc0[m] : acc1[m - 4];
        const int   dm = __shfl(pv0.x, q * 8 + m);
        if (dm == cur) {
          run += v;
        } else {
          atomicAdd(out + (size_t)cur * 32 + n, run);
          run = v; cur = dm;
        }
      }
      atomicAdd(out + (size_t)cur * 32 + n, run);
    }

    // ---- Rotate pipeline registers.
    pv0 = pv1; pv1 = pv2;
    nbA_c = nbA_n; nbB_c = nbB_n;
    bA0_c = bA0_n; bA1_c = bA1_n; bB0_c = bB0_n; bB1_c = bB1_n;
  }
}

extern "C" void kernel_launch(void* const* d_in, const int* in_sizes, int n_in,
                              void* d_out, int out_size, void* d_ws, size_t ws_size,
                              hipStream_t stream) {
  const float* atom  = (const float*)d_in[0];   // (100000, 32) f32
  const float* bondf = (const float*)d_in[1];   // (400000, 16) f32
  const int*   pairs = (const int*)d_in[2];     // (400000, 2) int32
  const float* Kmat  = (const float*)d_in[3];   // (16, 1024) f32
  const float* bias  = (const float*)d_in[4];   // (1024,) f32
  float* out = (float*)d_out;                   // (100000, 32) f32

  char* ws = (char*)d_ws;
  _Float16* atomh   = (_Float16*)(ws + OFF_ATOMH);
  _Float16* bondh_s = (_Float16*)(ws + OFF_BONDS);
  int2*     pairs_s = (int2*)    (ws + OFF_PAIRS);
  unsigned* hist    = (unsigned*)(ws + OFF_HIST);
  unsigned* base    = (unsigned*)(ws + OFF_BASE);
  unsigned* cnt     = (unsigned*)(ws + OFF_CNT);

  k_zero_conv<<<(K0_TOT + 1 + 255) / 256, 256, 0, stream>>>(
      atom, (float4*)out, (half4t*)atomh, (uint4*)hist, cnt);
  k_hist<<<(E + 255) / 256, 256, 0, stream>>>((const int2*)pairs, hist);
  k_scan<<<NCHUNK, 256, 0, stream>>>(hist, base, cnt);
  k_scatter<<<(E + 255) / 256, 256, 0, stream>>>(
      (const int2*)pairs, (const float4*)bondf, hist, base,
      pairs_s, (half8*)bondh_s);
  edge_sorted<<<NBLK, 256, 0, stream>>>(
      atomh, bondh_s, (const int*)pairs_s, Kmat, bias, out);
}

// Round 5
// 146.719 us; speedup vs baseline: 1.3317x; 1.3317x over previous
//
#include <hip/hip_runtime.h>
#include <hip/hip_fp16.h>

// EdgeNetwork: 3 dispatches, packed-f16 atomic accumulation.
//   k_prep: zero f16 accum + convert atom/bond f32->f16 into ws.
//   edge_fused: MFMA (P @ W), epilogue = global_atomic_pk_add_f16 (2 cols per
//     dword-RMW -> 6.4M transactions instead of 12.8M).
//   k_fin: accum f16 -> out f32.
//
// Journal:
// R0: hipLaunchCooperativeKernel silently no-ops under graph capture. NEVER.
// R1: occupancy x2 under the 12.8M-atomic wall -> neutral. Wall = atomic
//     TRANSACTION rate (~225G dword-RMW/s), not latency, not bytes.
// R3: dst-sort + run-merge cut atomics 3x (edge <43us) but +3 dispatches;
//     each extra dispatch costs ~8-10us in the timed path -> net LOSS.
// R4: launch_bounds(256,4) squeezed VGPR 80->64 -> scratch spills (FETCH
//     25->72MB). Never tighten launch_bounds here; (256,3)=80 VGPR is proven.
// R5 (this): halve transactions via pk_add_f16: even/odd lane pair shares one
//     __half2 atomic. f16 accum error ~0.1 vs threshold 0.32.

typedef _Float16 half8 __attribute__((ext_vector_type(8)));
typedef _Float16 half4t __attribute__((ext_vector_type(4)));
typedef float float4v __attribute__((ext_vector_type(4)));

constexpr int NA = 100000;
constexpr int E  = 400000;
constexpr int TILES = E / 32;          // 12500
constexpr int NBLK  = 768;             // 3 blocks/CU (proven spill-free config)
constexpr int HALFW = NBLK * 4 / 2;    // 1536 waves per column-half

// ---- workspace layout (bytes) ----
constexpr size_t OFF_ATOMH = 0;                           // f16[NA*32]  6.4 MB
constexpr size_t OFF_BONDH = (size_t)NA * 32 * 2;         // f16[E*16]  12.8 MB
constexpr size_t OFF_ACC   = OFF_BONDH + (size_t)E*16*2;  // f16[NA*32]  6.4 MB

constexpr int NZ4 = NA * 32 / 4;   // accum zeroing, half4t units (800k)
constexpr int NA4 = NA * 32 / 4;   // atom convert, float4 units  (800k)
constexpr int NB4 = E * 16 / 4;    // bond convert, float4 units  (1.6M)
constexpr int PREP_TOT = NZ4 + NA4 + NB4;

// ---- k_prep: zero f16 accum + convert atom/bond to f16 ----
__global__ void k_prep(const float* __restrict__ atom,
                       const float* __restrict__ bond,
                       half4t* __restrict__ accz,
                       half4t* __restrict__ atomh4,
                       half4t* __restrict__ bondh4) {
  int i = blockIdx.x * 256 + threadIdx.x;
  if (i < NZ4) {
    half4t z = { (_Float16)0.f, (_Float16)0.f, (_Float16)0.f, (_Float16)0.f };
    accz[i] = z;
  } else if (i < NZ4 + NA4) {
    int k = i - NZ4;
    float4 v = ((const float4*)atom)[k];
    half4t hh = { (_Float16)v.x, (_Float16)v.y, (_Float16)v.z, (_Float16)v.w };
    atomh4[k] = hh;
  } else if (i < PREP_TOT) {
    int k = i - NZ4 - NA4;
    float4 v = ((const float4*)bond)[k];
    half4t hh = { (_Float16)v.x, (_Float16)v.y, (_Float16)v.z, (_Float16)v.w };
    bondh4[k] = hh;
  }
}

static __device__ inline half8 splat8(_Float16 v) {
  half8 r = {v, v, v, v, v, v, v, v};
  return r;
}

// ---- edge_fused: MFMA + pk_add_f16 scatter ----
__global__ __launch_bounds__(256, 3)
void edge_fused(const _Float16* __restrict__ atomh,
                const _Float16* __restrict__ bondh,
                const int* __restrict__ pairs,
                const float* __restrict__ Kmat,
                const float* __restrict__ bias,
                _Float16* __restrict__ accum)
{
  const int tid  = threadIdx.x;
  const int lane = tid & 63;
  const int wid  = blockIdx.x * 4 + (tid >> 6);
  const int h    = wid & 1;          // column half this wave owns
  const int q    = lane >> 4;
  const int el   = lane & 15;
  const int n    = el + h * 16;      // output column
  const int j0   = q * 8;

  // W fragments for all 17 K-steps, register-resident.
  half8 Wr[17];
  #pragma unroll
  for (int s = 0; s < 17; ++s) {
    const float* src = (s < 16) ? (Kmat + s * 1024 + n * 32 + j0)
                                : (bias + n * 32 + j0);
    half8 w;
    #pragma unroll
    for (int j = 0; j < 8; ++j) w[j] = (_Float16)src[j];
    Wr[s] = w;
  }

  const int start  = wid >> 1;
  const int stride = HALFW;
  const int2* pairs2 = (const int2*)pairs;

  auto ldpv = [&](int t) -> int2 {
    const int tc = t < TILES ? t : TILES - 1;   // clamp: loads stay valid
    int2 v = make_int2(0, 0);
    if (lane < 32) v = pairs2[tc * 32 + lane];
    return v;
  };

  // ---- Pipeline prologue: stage tile `start`, start indices for start+stride.
  int2 pv0 = ldpv(start);
  int2 pv1 = ldpv(start + stride);

  half8 nbA_c, nbB_c, bA0_c, bA1_c, bB0_c, bB1_c;
  {
    const int aA = __shfl(pv0.y, el);
    const int aB = __shfl(pv0.y, el + 16);
    nbA_c = *(const half8*)(atomh + (size_t)aA * 32 + j0);
    nbB_c = *(const half8*)(atomh + (size_t)aB * 32 + j0);
    const _Float16* brA = bondh + (size_t)(start * 32 + el) * 16;
    const _Float16* brB = bondh + (size_t)(start * 32 + el + 16) * 16;
    bA0_c = *(const half8*)(brA);  bA1_c = *(const half8*)(brA + 8);
    bB0_c = *(const half8*)(brB);  bB1_c = *(const half8*)(brB + 8);
  }

  for (int t = start; t < TILES; t += stride) {
    const int tn = t + stride;

    // ---- Stage next tile first (loads in flight across this tile's compute).
    half8 nbA_n, nbB_n, bA0_n, bA1_n, bB0_n, bB1_n;
    {
      const int aA = __shfl(pv1.y, el);
      const int aB = __shfl(pv1.y, el + 16);
      nbA_n = *(const half8*)(atomh + (size_t)aA * 32 + j0);
      nbB_n = *(const half8*)(atomh + (size_t)aB * 32 + j0);
      const int tc = tn < TILES ? tn : TILES - 1;
      const _Float16* brA = bondh + (size_t)(tc * 32 + el) * 16;
      const _Float16* brB = bondh + (size_t)(tc * 32 + el + 16) * 16;
      bA0_n = *(const half8*)(brA);  bA1_n = *(const half8*)(brA + 8);
      bB0_n = *(const half8*)(brB);  bB1_n = *(const half8*)(brB + 8);
    }
    const int2 pv2 = ldpv(tn + stride);

    // ---- Compute current tile.
    float4v acc0 = {0.f, 0.f, 0.f, 0.f};
    float4v acc1 = {0.f, 0.f, 0.f, 0.f};
    #pragma unroll
    for (int s = 0; s < 16; ++s) {
      const _Float16 sA = (s < 8) ? bA0_c[s] : bA1_c[s - 8];
      const _Float16 sB = (s < 8) ? bB0_c[s] : bB1_c[s - 8];
      const half8 aAf = nbA_c * splat8(sA);
      const half8 aBf = nbB_c * splat8(sB);
      acc0 = __builtin_amdgcn_mfma_f32_16x16x32_f16(aAf, Wr[s], acc0, 0, 0, 0);
      acc1 = __builtin_amdgcn_mfma_f32_16x16x32_f16(aBf, Wr[s], acc1, 0, 0, 0);
    }
    acc0 = __builtin_amdgcn_mfma_f32_16x16x32_f16(nbA_c, Wr[16], acc0, 0, 0, 0);
    acc1 = __builtin_amdgcn_mfma_f32_16x16x32_f16(nbB_c, Wr[16], acc1, 0, 0, 0);

    // ---- Epilogue: packed-f16 atomics. Lanes (el even, el odd) share a
    // dword: even lane packs {self, partner} and issues ONE pk_add_f16.
    // All el-lanes of a given (q, r) share the same destination row.
    #pragma unroll
    for (int r = 0; r < 4; ++r) {
      {
        const int   s0 = __shfl(pv0.x, q * 4 + r);
        const float v  = acc0[r];
        const float pvx = __shfl_xor(v, 1);
        if (!(el & 1)) {
          union { _Float16 f[2]; __half2 h; } u;
          u.f[0] = (_Float16)v; u.f[1] = (_Float16)pvx;
          unsafeAtomicAdd(
              reinterpret_cast<__half2*>(accum + (size_t)s0 * 32 + n), u.h);
        }
      }
      {
        const int   s1 = __shfl(pv0.x, q * 4 + r + 16);
        const float v  = acc1[r];
        const float pvx = __shfl_xor(v, 1);
        if (!(el & 1)) {
          union { _Float16 f[2]; __half2 h; } u;
          u.f[0] = (_Float16)v; u.f[1] = (_Float16)pvx;
          unsafeAtomicAdd(
              reinterpret_cast<__half2*>(accum + (size_t)s1 * 32 + n), u.h);
        }
      }
    }

    // ---- Rotate pipeline registers.
    pv0 = pv1; pv1 = pv2;
    nbA_c = nbA_n; nbB_c = nbB_n;
    bA0_c = bA0_n; bA1_c = bA1_n; bB0_c = bB0_n; bB1_c = bB1_n;
  }
}

// ---- k_fin: accum f16 -> out f32 (full overwrite) ----
__global__ void k_fin(const half4t* __restrict__ acc4,
                      float4* __restrict__ out4) {
  int i = blockIdx.x * 256 + threadIdx.x;
  if (i >= NZ4) return;
  half4t v = acc4[i];
  out4[i] = make_float4((float)v[0], (float)v[1], (float)v[2], (float)v[3]);
}

extern "C" void kernel_launch(void* const* d_in, const int* in_sizes, int n_in,
                              void* d_out, int out_size, void* d_ws, size_t ws_size,
                              hipStream_t stream) {
  const float* atom  = (const float*)d_in[0];   // (100000, 32) f32
  const float* bondf = (const float*)d_in[1];   // (400000, 16) f32
  const int*   pairs = (const int*)d_in[2];     // (400000, 2) int32
  const float* Kmat  = (const float*)d_in[3];   // (16, 1024) f32
  const float* bias  = (const float*)d_in[4];   // (1024,) f32
  float* out = (float*)d_out;                   // (100000, 32) f32

  char* ws = (char*)d_ws;
  _Float16* atomh = (_Float16*)(ws + OFF_ATOMH);
  _Float16* bondh = (_Float16*)(ws + OFF_BONDH);
  _Float16* accum = (_Float16*)(ws + OFF_ACC);

  k_prep<<<(PREP_TOT + 255) / 256, 256, 0, stream>>>(
      atom, bondf, (half4t*)accum, (half4t*)atomh, (half4t*)bondh);
  edge_fused<<<NBLK, 256, 0, stream>>>(atomh, bondh, pairs, Kmat, bias, accum);
  k_fin<<<(NZ4 + 255) / 256, 256, 0, stream>>>((const half4t*)accum,
                                               (float4*)out);
}

// Round 6
// 128.187 us; speedup vs baseline: 1.5242x; 1.1446x over previous
//
#include <hip/hip_runtime.h>
#include <hip/hip_fp16.h>

// EdgeNetwork: 3 dispatches, full-row waves + packed-f16 atomics.
//   k_prep: zero f16 accum + convert atom/bond f32->f16 into ws.
//   edge_fused: each wave computes 16 edges x ALL 32 cols (two n-half MFMAs
//     per K-step; h0 W-half in 68 VGPRs, h1 W-half read from LDS). Epilogue:
//     ONE pk-atomic instruction covers an edge's entire 64B accum row
//     (even lanes: cols el,el+1 from acc_h0; odd lanes: 15+el,16+el from
//     acc_h1) -> 400k atomic sector-touches (was 800k).
//   k_fin: accum f16 -> out f32.
//
// Journal:
// R0: hipLaunchCooperativeKernel silently no-ops under graph capture. NEVER.
// R1: occupancy x2 -> neutral. Not latency-bound.
// R3: dst-sort cut atomic sector-touches ~3x -> edge <=43us, but +3 dispatches
//     (~9us each) -> net loss. ~74us of harness overhead is FIXED.
// R4: launch_bounds(256,4) -> VGPR squeezed 80->64, scratch spills. Keep (256,3).
// R5: pk_add_f16 halved atomic DWORDS (WRITE 50->25MB), time UNCHANGED ->
//     wall is atomic SECTOR-TOUCHES at the coherence point (800k constant
//     across R0/R2/R5 at ~55us; R3's 270k ran <=43us), not dword count.
// R6 (this): halve sector-touches: full-row waves, one atomic instr per row.

typedef _Float16 half8 __attribute__((ext_vector_type(8)));
typedef _Float16 half4t __attribute__((ext_vector_type(4)));
typedef float float4v __attribute__((ext_vector_type(4)));

constexpr int NA = 100000;
constexpr int E  = 400000;
constexpr int GRP   = E / 16;          // 25000 16-edge groups
constexpr int NBLK  = 768;             // 3 blocks/CU (proven spill-free)
constexpr int NWAVE = NBLK * 4;        // 3072 persistent waves

// ---- workspace layout (bytes) ----
constexpr size_t OFF_ATOMH = 0;                           // f16[NA*32]  6.4 MB
constexpr size_t OFF_BONDH = (size_t)NA * 32 * 2;         // f16[E*16]  12.8 MB
constexpr size_t OFF_ACC   = OFF_BONDH + (size_t)E*16*2;  // f16[NA*32]  6.4 MB

constexpr int NZ4 = NA * 32 / 4;   // accum zeroing, half4t units (800k)
constexpr int NA4 = NA * 32 / 4;   // atom convert, float4 units  (800k)
constexpr int NB4 = E * 16 / 4;    // bond convert, float4 units  (1.6M)
constexpr int PREP_TOT = NZ4 + NA4 + NB4;

constexpr int WSTRIDE = 80;        // LDS bytes per n-row (16B-aligned, 2-way)

// ---- k_prep: zero f16 accum + convert atom/bond to f16 ----
__global__ void k_prep(const float* __restrict__ atom,
                       const float* __restrict__ bond,
                       half4t* __restrict__ accz,
                       half4t* __restrict__ atomh4,
                       half4t* __restrict__ bondh4) {
  int i = blockIdx.x * 256 + threadIdx.x;
  if (i < NZ4) {
    half4t z = { (_Float16)0.f, (_Float16)0.f, (_Float16)0.f, (_Float16)0.f };
    accz[i] = z;
  } else if (i < NZ4 + NA4) {
    int k = i - NZ4;
    float4 v = ((const float4*)atom)[k];
    half4t hh = { (_Float16)v.x, (_Float16)v.y, (_Float16)v.z, (_Float16)v.w };
    atomh4[k] = hh;
  } else if (i < PREP_TOT) {
    int k = i - NZ4 - NA4;
    float4 v = ((const float4*)bond)[k];
    half4t hh = { (_Float16)v.x, (_Float16)v.y, (_Float16)v.z, (_Float16)v.w };
    bondh4[k] = hh;
  }
}

static __device__ inline half8 splat8(_Float16 v) {
  half8 r = {v, v, v, v, v, v, v, v};
  return r;
}

// ---- edge_fused: full-row MFMA + one-pk-instruction-per-row scatter ----
__global__ __launch_bounds__(256, 3)
void edge_fused(const _Float16* __restrict__ atomh,
                const _Float16* __restrict__ bondh,
                const int* __restrict__ pairs,
                const float* __restrict__ Kmat,
                const float* __restrict__ bias,
                _Float16* __restrict__ accum)
{
  __shared__ __attribute__((aligned(16))) char wl[17 * 16 * WSTRIDE];

  const int tid  = threadIdx.x;
  const int lane = tid & 63;
  const int wid  = blockIdx.x * 4 + (tid >> 6);
  const int q    = lane >> 4;
  const int el   = lane & 15;
  const int j0   = q * 8;

  // Fill LDS with the h1 half of W (cols 16..31) + bias row, f16.
  // Element i = s*512 + n16*32 + j; row (s,n16) at byte (s*16+n16)*80.
  for (int i4 = tid; i4 < 17 * 16 * 32 / 4; i4 += 256) {
    const int i   = i4 * 4;
    const int s   = i >> 9;
    const int r   = i & 511;
    const int n16 = r >> 5;
    const int j   = r & 31;
    const float* src = (s < 16) ? (Kmat + s * 1024 + (n16 + 16) * 32 + j)
                                : (bias + (n16 + 16) * 32 + j);
    float4 v = *(const float4*)src;
    half4t hh = { (_Float16)v.x, (_Float16)v.y, (_Float16)v.z, (_Float16)v.w };
    *(half4t*)(wl + (s * 16 + n16) * WSTRIDE + j * 2) = hh;
  }

  // h0 W-half (cols 0..15) register-resident: identical to proven Wr, h=0.
  half8 Wr[17];
  #pragma unroll
  for (int s = 0; s < 17; ++s) {
    const float* src = (s < 16) ? (Kmat + s * 1024 + el * 32 + j0)
                                : (bias + el * 32 + j0);
    half8 w;
    #pragma unroll
    for (int j = 0; j < 8; ++j) w[j] = (_Float16)src[j];
    Wr[s] = w;
  }

  __syncthreads();

  const int2* pairs2 = (const int2*)pairs;
  const char* wb = wl + el * WSTRIDE + q * 16;   // h1 frag base (n = el+16)

  auto ldpv = [&](int g) -> int2 {
    const int gc = g < GRP ? g : GRP - 1;        // clamp: loads stay valid
    int2 v = make_int2(0, 0);
    if (lane < 16) v = pairs2[gc * 16 + lane];
    return v;
  };

  // ---- Pipeline prologue: stage group `wid`, start indices for next.
  int2 pv0 = ldpv(wid);
  int2 pv1 = ldpv(wid + NWAVE);

  half8 nb_c, b0_c, b1_c;
  {
    const int a = __shfl(pv0.y, el);
    nb_c = *(const half8*)(atomh + (size_t)a * 32 + j0);
    const _Float16* br = bondh + (size_t)(wid * 16 + el) * 16;
    b0_c = *(const half8*)(br);  b1_c = *(const half8*)(br + 8);
  }

  for (int g = wid; g < GRP; g += NWAVE) {
    const int gn = g + NWAVE;

    // ---- Stage next group (loads in flight across this group's compute).
    half8 nb_n, b0_n, b1_n;
    {
      const int a = __shfl(pv1.y, el);
      nb_n = *(const half8*)(atomh + (size_t)a * 32 + j0);
      const int gc = gn < GRP ? gn : GRP - 1;
      const _Float16* br = bondh + (size_t)(gc * 16 + el) * 16;
      b0_n = *(const half8*)(br);  b1_n = *(const half8*)(br + 8);
    }
    const int2 pv2 = ldpv(gn + NWAVE);

    // Opaque zero (SGPR) so the loop-invariant LDS reads are not hoisted
    // (LICM would make 17 frags live at once -> register blowup).
    int zz;
    asm volatile("s_mov_b32 %0, 0" : "=s"(zz));
    const char* wbz = wb + zz;

    // ---- Compute: 16 edges x 32 cols; acc_h0 = cols el(+1..), acc_h1 = +16.
    float4v a0 = {0.f, 0.f, 0.f, 0.f};
    float4v a1 = {0.f, 0.f, 0.f, 0.f};
    #pragma unroll
    for (int s = 0; s < 16; ++s) {
      const _Float16 sc = (s < 8) ? b0_c[s] : b1_c[s - 8];
      const half8 af = nb_c * splat8(sc);
      const half8 w1 = *(const half8*)(wbz + s * 16 * WSTRIDE);
      a0 = __builtin_amdgcn_mfma_f32_16x16x32_f16(af, Wr[s], a0, 0, 0, 0);
      a1 = __builtin_amdgcn_mfma_f32_16x16x32_f16(af, w1,    a1, 0, 0, 0);
    }
    {
      const half8 w1 = *(const half8*)(wbz + 16 * 16 * WSTRIDE);
      a0 = __builtin_amdgcn_mfma_f32_16x16x32_f16(nb_c, Wr[16], a0, 0, 0, 0);
      a1 = __builtin_amdgcn_mfma_f32_16x16x32_f16(nb_c, w1,     a1, 0, 0, 0);
    }

    // ---- Epilogue: one pk-atomic instruction per 4 rows covers each edge's
    // FULL 64B accum row. Even lane el: cols (el, el+1) from acc_h0; odd lane
    // el: cols (15+el, 16+el) from acc_h1 (values via shfl_xor with neighbor).
    const bool ev = !(el & 1);
    #pragma unroll
    for (int r = 0; r < 4; ++r) {
      const int   d  = __shfl(pv0.x, q * 4 + r);
      const float v0 = a0[r], v1 = a1[r];
      const float p0 = __shfl_xor(v0, 1);
      const float p1 = __shfl_xor(v1, 1);
      union { _Float16 f[2]; __half2 h; } u;
      u.f[0] = ev ? (_Float16)v0 : (_Float16)p1;
      u.f[1] = ev ? (_Float16)p0 : (_Float16)v1;
      const int col = ev ? el : (15 + el);
      unsafeAtomicAdd(reinterpret_cast<__half2*>(
                          accum + (size_t)d * 32 + col), u.h);
    }

    // ---- Rotate pipeline registers.
    pv0 = pv1; pv1 = pv2;
    nb_c = nb_n; b0_c = b0_n; b1_c = b1_n;
  }
}

// ---- k_fin: accum f16 -> out f32 (full overwrite) ----
__global__ void k_fin(const half4t* __restrict__ acc4,
                      float4* __restrict__ out4) {
  int i = blockIdx.x * 256 + threadIdx.x;
  if (i >= NZ4) return;
  half4t v = acc4[i];
  out4[i] = make_float4((float)v[0], (float)v[1], (float)v[2], (float)v[3]);
}

extern "C" void kernel_launch(void* const* d_in, const int* in_sizes, int n_in,
                              void* d_out, int out_size, void* d_ws, size_t ws_size,
                              hipStream_t stream) {
  const float* atom  = (const float*)d_in[0];   // (100000, 32) f32
  const float* bondf = (const float*)d_in[1];   // (400000, 16) f32
  const int*   pairs = (const int*)d_in[2];     // (400000, 2) int32
  const float* Kmat  = (const float*)d_in[3];   // (16, 1024) f32
  const float* bias  = (const float*)d_in[4];   // (1024,) f32
  float* out = (float*)d_out;                   // (100000, 32) f32

  char* ws = (char*)d_ws;
  _Float16* atomh = (_Float16*)(ws + OFF_ATOMH);
  _Float16* bondh = (_Float16*)(ws + OFF_BONDH);
  _Float16* accum = (_Float16*)(ws + OFF_ACC);

  k_prep<<<(PREP_TOT + 255) / 256, 256, 0, stream>>>(
      atom, bondf, (half4t*)accum, (half4t*)atomh, (half4t*)bondh);
  edge_fused<<<NBLK, 256, 0, stream>>>(atomh, bondh, pairs, Kmat, bias, accum);
  k_fin<<<(NZ4 + 255) / 256, 256, 0, stream>>>((const half4t*)accum,
                                               (float4*)out);
}